// Round 8
// baseline (119.138 us; speedup 1.0000x reference)
//
#include <hip/hip_runtime.h>
#include <math.h>

// Problem constants (from reference)
constexpr int B_  = 4;
constexpr int NQ_ = 2048;
constexpr int NK_ = 2048;
constexpr int C_  = 4;
constexpr int OUT_ = 64;
constexpr int H_  = 16;
constexpr float WINDOW_ = 0.25f;

constexpr int   TAB_   = 2048;                 // value-table cells over [0, WINDOW)
constexpr float SCALE_ = TAB_ / WINDOW_;       // 8192
constexpr int   QT_    = 16;                   // queries per block (4 per wave)
constexpr int   SLOT_  = 1024;                 // padded keys per (batch,chan)
constexpr int   NBIN_  = 32;                   // position bins over [0,1)
constexpr float SENT_  = 4e9f;                 // sentinel position (out of window)

// d_ws layout
constexpr size_t OFF_TAB  = 0;                         // 2048 float = 8 KB
constexpr size_t OFF_SORT = 8192;                      // 16 slots * 1024 float2 = 128 KB
constexpr size_t OFF_BINS = 8192 + 16 * SLOT_ * 8;     // 16 slots * 33 int

// ---------------------------------------------------------------------------
// Preprocess (24 blocks):
//  blocks 0..7  : tabulate |MLP(d)| at each cell CENTER (single fp32/cell).
//                 Const-per-cell err <= |f'|*h/2 ~ 1e-4 << 1.09e-2 threshold.
//                 Single-value table => ds_read_b32 gather (2-way bank
//                 aliasing = free on gfx950, vs b64's guaranteed >=4-way).
//  blocks 8..23 : counting sort of one (batch,chan)'s keys into 32 position
//                 bins (order within bin irrelevant under sum-reduction);
//                 exclusive prefix = CDF for window skip; sentinel padded.
// ---------------------------------------------------------------------------
__global__ __launch_bounds__(256) void preprocess(
    const float* __restrict__ key_pos,
    const float* __restrict__ values,
    const int*   __restrict__ key_chan,
    const float* __restrict__ w0, const float* __restrict__ b0,
    const float* __restrict__ w1, const float* __restrict__ b1,
    const float* __restrict__ w2, const float* __restrict__ b2,
    const float* __restrict__ w3, const float* __restrict__ b3,
    float* __restrict__ tab,
    float2* __restrict__ sorted,
    int*    __restrict__ bins)
{
    const int tid = threadIdx.x;

    if (blockIdx.x < 8) {
        // ---- table build: |f| at cell center ----
        const int i = blockIdx.x * 256 + tid;
        const float x = ((float)i + 0.5f) * (1.0f / SCALE_);
        float h[H_], g[H_];
        #pragma unroll
        for (int j = 0; j < H_; ++j)
            h[j] = fmaxf(fmaf(x, w0[j], b0[j]), 0.f);
        #pragma unroll
        for (int j = 0; j < H_; ++j) {
            float a = b1[j];
            #pragma unroll
            for (int k = 0; k < H_; ++k) a = fmaf(w1[j * H_ + k], h[k], a);
            g[j] = fmaxf(a, 0.f);
        }
        #pragma unroll
        for (int j = 0; j < H_; ++j) {
            float a = b2[j];
            #pragma unroll
            for (int k = 0; k < H_; ++k) a = fmaf(w2[j * H_ + k], g[k], a);
            h[j] = fmaxf(a, 0.f);
        }
        float a = b3[0];
        #pragma unroll
        for (int k = 0; k < H_; ++k) a = fmaf(w3[k], h[k], a);
        tab[i] = fabsf(a);
        return;
    }

    // ---- counting sort for one (batch,chan) ----
    const int slot = blockIdx.x - 8;      // 0..15
    const int b    = slot >> 2;
    const int c    = slot & 3;

    __shared__ int   hist[NBIN_ + 1];
    __shared__ int   ofs [NBIN_];
    __shared__ float lpos[SLOT_];
    __shared__ float lval[SLOT_];

    if (tid <= NBIN_) hist[tid] = 0;
    __syncthreads();

    const float* kp = key_pos  + b * NK_;
    const float* vv = values   + b * NK_;
    const int*   cc = key_chan + b * NK_;

    for (int i = tid; i < NK_; i += 256) {
        if (cc[i] == c) {
            const int bin = min((int)(kp[i] * (float)NBIN_), NBIN_ - 1);
            atomicAdd(&hist[bin], 1);
        }
    }
    __syncthreads();

    if (tid == 0) {
        int run = 0;
        #pragma unroll
        for (int t = 0; t < NBIN_; ++t) {
            const int h = hist[t];
            hist[t] = run; ofs[t] = run; run += h;
        }
        hist[NBIN_] = run;
    }
    __syncthreads();

    const int cnt = hist[NBIN_];          // ~512 << SLOT_
    if (tid <= NBIN_) bins[slot * (NBIN_ + 1) + tid] = hist[tid];

    for (int i = tid; i < NK_; i += 256) {
        if (cc[i] == c) {
            const float p   = kp[i];
            const int   bin = min((int)(p * (float)NBIN_), NBIN_ - 1);
            const int   idx = atomicAdd(&ofs[bin], 1);
            lpos[idx] = p; lval[idx] = vv[i];
        }
    }
    __syncthreads();

    for (int i = tid; i < SLOT_; i += 256)
        sorted[slot * SLOT_ + i] =
            (i < cnt) ? make_float2(lpos[i], lval[i]) : make_float2(SENT_, 0.f);
}

// ---------------------------------------------------------------------------
// Main: block = 16 queries of one batch; wave = 4 queries. 8 KB value table
// in LDS; per pair ~9 VALU + 1 dwordx2 + 1 ds_read_b32 gather. CDF indexing
// skips out-of-window bins; strict dd<WINDOW mask exactly kills bin-boundary
// overshoot, overshot slots and sentinels — no lane masks needed.
// ---------------------------------------------------------------------------
__global__ __launch_bounds__(256) void setconv_main(
    const float*  __restrict__ queries,
    const float2* __restrict__ sorted,
    const int*    __restrict__ bins,
    const float*  __restrict__ tab,
    const float*  __restrict__ wd, const float* __restrict__ bd,
    const float*  __restrict__ wr, const float* __restrict__ br,
    float* __restrict__ out)
{
    __shared__ __align__(16) float ltab[TAB_];

    const int tid = threadIdx.x;

    // stage table: 512 float4s, 2 per thread
    {
        const float4* t4 = (const float4*)tab;
        float4*       l4 = (float4*)ltab;
        #pragma unroll
        for (int i = 0; i < TAB_ / 4 / 256; ++i)
            l4[i * 256 + tid] = t4[i * 256 + tid];
    }
    __syncthreads();

    const int blk  = blockIdx.x;        // 512 blocks: b = blk>>7, tile = blk&127
    const int b    = blk >> 7;
    const int tile = blk & 127;
    const int wave = tid >> 6;
    const int lane = tid & 63;

    const float wd0 = wd[0];
    const float bd0 = bd[0];

    float wrow[8];
    #pragma unroll
    for (int j = 0; j < 8; ++j) wrow[j] = wr[lane * 8 + j];
    const float brv = br[lane];

    #pragma unroll
    for (int qq = 0; qq < 4; ++qq) {
        const int   qi   = tile * QT_ + wave * 4 + qq;
        const float qpos = queries[b * NQ_ + qi];

        int lo_bin = (int)floorf((qpos - WINDOW_) * (float)NBIN_);
        lo_bin = (lo_bin < 0) ? 0 : ((lo_bin > NBIN_) ? NBIN_ : lo_bin);
        int hi_bin = (int)ceilf((qpos + WINDOW_) * (float)NBIN_);
        hi_bin = (hi_bin < 0) ? 0 : ((hi_bin > NBIN_) ? NBIN_ : hi_bin);

        float dens[4], num[4];
        #pragma unroll
        for (int c = 0; c < 4; ++c) {
            const int slot = b * 4 + c;
            const int* bs  = bins + slot * (NBIN_ + 1);
            const int lo = bs[lo_bin] & ~63;
            const int hi = bs[hi_bin];
            const float2* seg = sorted + slot * SLOT_;

            float d = 0.f, n = 0.f;
            for (int k = lo; k < hi; k += 64) {
                const float2 pv = seg[k + lane];      // may overshoot hi: masked
                const float dd  = fabsf(pv.x - qpos);
                const float t   = fminf(dd * SCALE_, (float)(TAB_ - 1));
                const float tv  = ltab[(int)t];       // ds_read_b32 gather
                const float w   = (dd < WINDOW_) ? tv : 0.f;
                d += w;
                n  = fmaf(w, pv.y, n);
            }
            dens[c] = d; num[c] = n;
        }

        // 64-lane butterfly: every lane ends with the full sums
        #pragma unroll
        for (int off = 32; off >= 1; off >>= 1) {
            #pragma unroll
            for (int c = 0; c < 4; ++c) {
                dens[c] += __shfl_xor(dens[c], off, 64);
                num [c] += __shfl_xor(num [c], off, 64);
            }
        }

        // fused epilogue, redundantly per lane; lane == output channel
        float acc = brv;
        #pragma unroll
        for (int c = 0; c < 4; ++c) {
            const float tgt = num[c] / (dens[c] + 1e-5f);
            const float x   = (dens[c] * 0.1f - 1.0f) * wd0 + bd0;
            const float df  = 1.0f / (1.0f + expf(-x));
            acc = fmaf(wrow[2 * c],     tgt, acc);
            acc = fmaf(wrow[2 * c + 1], df,  acc);
        }
        out[(b * NQ_ + qi) * OUT_ + lane] = acc;
    }
}

extern "C" void kernel_launch(void* const* d_in, const int* in_sizes, int n_in,
                              void* d_out, int out_size, void* d_ws, size_t ws_size,
                              hipStream_t stream) {
    (void)in_sizes; (void)n_in; (void)out_size; (void)ws_size;

    char* ws = (char*)d_ws;
    float*  tab    = (float*) (ws + OFF_TAB);
    float2* sorted = (float2*)(ws + OFF_SORT);
    int*    bins   = (int*)   (ws + OFF_BINS);

    preprocess<<<dim3(24), dim3(256), 0, stream>>>(
        (const float*)d_in[0],  // key_pos
        (const float*)d_in[2],  // values
        (const int*)  d_in[3],  // key_chan
        (const float*)d_in[4],  (const float*)d_in[5],   // w0 b0
        (const float*)d_in[6],  (const float*)d_in[7],   // w1 b1
        (const float*)d_in[8],  (const float*)d_in[9],   // w2 b2
        (const float*)d_in[10], (const float*)d_in[11],  // w3 b3
        tab, sorted, bins);

    setconv_main<<<dim3(B_ * (NQ_ / QT_)), dim3(256), 0, stream>>>(
        (const float*)d_in[1],  // queries
        sorted, bins, tab,
        (const float*)d_in[12], (const float*)d_in[13],  // wd bd
        (const float*)d_in[14], (const float*)d_in[15],  // wr br
        (float*)d_out);
}

// Round 9
// 111.197 us; speedup vs baseline: 1.0714x; 1.0714x over previous
//
#include <hip/hip_runtime.h>
#include <math.h>

// Problem constants (from reference)
constexpr int B_  = 4;
constexpr int NQ_ = 2048;
constexpr int NK_ = 2048;
constexpr int C_  = 4;
constexpr int OUT_ = 64;
constexpr int H_  = 16;
constexpr float WINDOW_ = 0.25f;

constexpr int   TAB_   = 2048;                 // value-table cells over [0, WINDOW)
constexpr float SCALE_ = TAB_ / WINDOW_;       // 8192
constexpr int   QT_    = 8;                    // queries per block (2 per wave)
constexpr int   SLOT_  = 1024;                 // padded keys per (batch,chan)
constexpr int   NBIN_  = 32;                   // position bins over [0,1)
constexpr float SENT_  = 4e9f;                 // sentinel position (out of window)

// d_ws layout
constexpr size_t OFF_TAB  = 0;                         // 2048 float = 8 KB
constexpr size_t OFF_SORT = 8192;                      // 16 slots * 1024 float2 = 128 KB
constexpr size_t OFF_BINS = 8192 + 16 * SLOT_ * 8;     // 16 slots * 33 int

// ---------------------------------------------------------------------------
// Preprocess (24 blocks):
//  blocks 0..7  : tabulate |MLP(d)| at each cell CENTER (single fp32/cell).
//                 Const-per-cell err <= |f'|*h/2 ~ 1e-4 << 1.09e-2 threshold.
//                 Single-value table => ds_read_b32 gather (2-way bank
//                 aliasing = free on gfx950, vs b64's guaranteed >=4-way).
//  blocks 8..23 : counting sort of one (batch,chan)'s keys into 32 position
//                 bins (order within bin irrelevant under sum-reduction);
//                 exclusive prefix = CDF for window skip; sentinel padded.
// ---------------------------------------------------------------------------
__global__ __launch_bounds__(256) void preprocess(
    const float* __restrict__ key_pos,
    const float* __restrict__ values,
    const int*   __restrict__ key_chan,
    const float* __restrict__ w0, const float* __restrict__ b0,
    const float* __restrict__ w1, const float* __restrict__ b1,
    const float* __restrict__ w2, const float* __restrict__ b2,
    const float* __restrict__ w3, const float* __restrict__ b3,
    float* __restrict__ tab,
    float2* __restrict__ sorted,
    int*    __restrict__ bins)
{
    const int tid = threadIdx.x;

    if (blockIdx.x < 8) {
        // ---- table build: |f| at cell center ----
        const int i = blockIdx.x * 256 + tid;
        const float x = ((float)i + 0.5f) * (1.0f / SCALE_);
        float h[H_], g[H_];
        #pragma unroll
        for (int j = 0; j < H_; ++j)
            h[j] = fmaxf(fmaf(x, w0[j], b0[j]), 0.f);
        #pragma unroll
        for (int j = 0; j < H_; ++j) {
            float a = b1[j];
            #pragma unroll
            for (int k = 0; k < H_; ++k) a = fmaf(w1[j * H_ + k], h[k], a);
            g[j] = fmaxf(a, 0.f);
        }
        #pragma unroll
        for (int j = 0; j < H_; ++j) {
            float a = b2[j];
            #pragma unroll
            for (int k = 0; k < H_; ++k) a = fmaf(w2[j * H_ + k], g[k], a);
            h[j] = fmaxf(a, 0.f);
        }
        float a = b3[0];
        #pragma unroll
        for (int k = 0; k < H_; ++k) a = fmaf(w3[k], h[k], a);
        tab[i] = fabsf(a);
        return;
    }

    // ---- counting sort for one (batch,chan) ----
    const int slot = blockIdx.x - 8;      // 0..15
    const int b    = slot >> 2;
    const int c    = slot & 3;

    __shared__ int   hist[NBIN_ + 1];
    __shared__ int   ofs [NBIN_];
    __shared__ float lpos[SLOT_];
    __shared__ float lval[SLOT_];

    if (tid <= NBIN_) hist[tid] = 0;
    __syncthreads();

    const float* kp = key_pos  + b * NK_;
    const float* vv = values   + b * NK_;
    const int*   cc = key_chan + b * NK_;

    for (int i = tid; i < NK_; i += 256) {
        if (cc[i] == c) {
            const int bin = min((int)(kp[i] * (float)NBIN_), NBIN_ - 1);
            atomicAdd(&hist[bin], 1);
        }
    }
    __syncthreads();

    if (tid == 0) {
        int run = 0;
        #pragma unroll
        for (int t = 0; t < NBIN_; ++t) {
            const int h = hist[t];
            hist[t] = run; ofs[t] = run; run += h;
        }
        hist[NBIN_] = run;
    }
    __syncthreads();

    const int cnt = hist[NBIN_];          // ~512 << SLOT_
    if (tid <= NBIN_) bins[slot * (NBIN_ + 1) + tid] = hist[tid];

    for (int i = tid; i < NK_; i += 256) {
        if (cc[i] == c) {
            const float p   = kp[i];
            const int   bin = min((int)(p * (float)NBIN_), NBIN_ - 1);
            const int   idx = atomicAdd(&ofs[bin], 1);
            lpos[idx] = p; lval[idx] = vv[i];
        }
    }
    __syncthreads();

    for (int i = tid; i < SLOT_; i += 256)
        sorted[slot * SLOT_ + i] =
            (i < cnt) ? make_float2(lpos[i], lval[i]) : make_float2(SENT_, 0.f);
}

// ---------------------------------------------------------------------------
// Main: block = 8 queries of one batch; wave = one query (x2); 1024 blocks
// = 4 blocks/CU (16 waves/CU — the latency-hiding level R7 validated; R8's
// 512-block variant regressed +14 µs). 8 KB value table in LDS; per pair
// ~9 VALU + 1 dwordx2 + 1 ds_read_b32 gather. CDF indexing skips
// out-of-window bins; strict dd<WINDOW mask exactly kills bin-boundary
// overshoot, overshot slots and sentinels — no lane masks needed.
// ---------------------------------------------------------------------------
__global__ __launch_bounds__(256) void setconv_main(
    const float*  __restrict__ queries,
    const float2* __restrict__ sorted,
    const int*    __restrict__ bins,
    const float*  __restrict__ tab,
    const float*  __restrict__ wd, const float* __restrict__ bd,
    const float*  __restrict__ wr, const float* __restrict__ br,
    float* __restrict__ out)
{
    __shared__ __align__(16) float ltab[TAB_];

    const int tid = threadIdx.x;

    // stage table: 512 float4s, 2 per thread
    {
        const float4* t4 = (const float4*)tab;
        float4*       l4 = (float4*)ltab;
        #pragma unroll
        for (int i = 0; i < TAB_ / 4 / 256; ++i)
            l4[i * 256 + tid] = t4[i * 256 + tid];
    }
    __syncthreads();

    const int blk  = blockIdx.x;        // 1024 blocks: b = blk>>8, tile = blk&255
    const int b    = blk >> 8;
    const int tile = blk & 255;
    const int wave = tid >> 6;
    const int lane = tid & 63;

    const float wd0 = wd[0];
    const float bd0 = bd[0];

    float wrow[8];
    #pragma unroll
    for (int j = 0; j < 8; ++j) wrow[j] = wr[lane * 8 + j];
    const float brv = br[lane];

    #pragma unroll
    for (int qq = 0; qq < 2; ++qq) {
        const int   qi   = tile * QT_ + wave * 2 + qq;
        const float qpos = queries[b * NQ_ + qi];

        int lo_bin = (int)floorf((qpos - WINDOW_) * (float)NBIN_);
        lo_bin = (lo_bin < 0) ? 0 : ((lo_bin > NBIN_) ? NBIN_ : lo_bin);
        int hi_bin = (int)ceilf((qpos + WINDOW_) * (float)NBIN_);
        hi_bin = (hi_bin < 0) ? 0 : ((hi_bin > NBIN_) ? NBIN_ : hi_bin);

        float dens[4], num[4];
        #pragma unroll
        for (int c = 0; c < 4; ++c) {
            const int slot = b * 4 + c;
            const int* bs  = bins + slot * (NBIN_ + 1);
            const int lo = bs[lo_bin] & ~63;
            const int hi = bs[hi_bin];
            const float2* seg = sorted + slot * SLOT_;

            float d = 0.f, n = 0.f;
            for (int k = lo; k < hi; k += 64) {
                const float2 pv = seg[k + lane];      // may overshoot hi: masked
                const float dd  = fabsf(pv.x - qpos);
                const float t   = fminf(dd * SCALE_, (float)(TAB_ - 1));
                const float tv  = ltab[(int)t];       // ds_read_b32 gather
                const float w   = (dd < WINDOW_) ? tv : 0.f;
                d += w;
                n  = fmaf(w, pv.y, n);
            }
            dens[c] = d; num[c] = n;
        }

        // 64-lane butterfly: every lane ends with the full sums
        #pragma unroll
        for (int off = 32; off >= 1; off >>= 1) {
            #pragma unroll
            for (int c = 0; c < 4; ++c) {
                dens[c] += __shfl_xor(dens[c], off, 64);
                num [c] += __shfl_xor(num [c], off, 64);
            }
        }

        // fused epilogue, redundantly per lane; lane == output channel
        float acc = brv;
        #pragma unroll
        for (int c = 0; c < 4; ++c) {
            const float tgt = num[c] / (dens[c] + 1e-5f);
            const float x   = (dens[c] * 0.1f - 1.0f) * wd0 + bd0;
            const float df  = 1.0f / (1.0f + expf(-x));
            acc = fmaf(wrow[2 * c],     tgt, acc);
            acc = fmaf(wrow[2 * c + 1], df,  acc);
        }
        out[(b * NQ_ + qi) * OUT_ + lane] = acc;
    }
}

extern "C" void kernel_launch(void* const* d_in, const int* in_sizes, int n_in,
                              void* d_out, int out_size, void* d_ws, size_t ws_size,
                              hipStream_t stream) {
    (void)in_sizes; (void)n_in; (void)out_size; (void)ws_size;

    char* ws = (char*)d_ws;
    float*  tab    = (float*) (ws + OFF_TAB);
    float2* sorted = (float2*)(ws + OFF_SORT);
    int*    bins   = (int*)   (ws + OFF_BINS);

    preprocess<<<dim3(24), dim3(256), 0, stream>>>(
        (const float*)d_in[0],  // key_pos
        (const float*)d_in[2],  // values
        (const int*)  d_in[3],  // key_chan
        (const float*)d_in[4],  (const float*)d_in[5],   // w0 b0
        (const float*)d_in[6],  (const float*)d_in[7],   // w1 b1
        (const float*)d_in[8],  (const float*)d_in[9],   // w2 b2
        (const float*)d_in[10], (const float*)d_in[11],  // w3 b3
        tab, sorted, bins);

    setconv_main<<<dim3(B_ * (NQ_ / QT_)), dim3(256), 0, stream>>>(
        (const float*)d_in[1],  // queries
        sorted, bins, tab,
        (const float*)d_in[12], (const float*)d_in[13],  // wd bd
        (const float*)d_in[14], (const float*)d_in[15],  // wr br
        (float*)d_out);
}

// Round 10
// 105.041 us; speedup vs baseline: 1.1342x; 1.0586x over previous
//
#include <hip/hip_runtime.h>
#include <math.h>

// Problem constants (from reference)
constexpr int B_  = 4;
constexpr int NQ_ = 2048;
constexpr int NK_ = 2048;
constexpr int C_  = 4;
constexpr int OUT_ = 64;
constexpr int H_  = 16;
constexpr float WINDOW_ = 0.25f;

constexpr int   TAB_   = 4096;                 // value-table cells over [0, WINDOW)
constexpr float SCALE_ = TAB_ / WINDOW_;       // 16384
constexpr int   QT_    = 8;                    // queries per block (2 per wave)
constexpr int   SLOT_  = 1024;                 // padded keys per (batch,chan)
constexpr int   NBIN_  = 16;                   // position bins over [0,1)
constexpr float SENT_  = 4e9f;                 // sentinel position (out of window)

// d_ws layout
constexpr size_t OFF_TAB  = 0;                         // 4096 float = 16 KB
constexpr size_t OFF_SORT = 16384;                     // 16 slots * 1024 float2 = 128 KB
constexpr size_t OFF_BINS = 16384 + 16 * SLOT_ * 8;    // 16 slots * 17 int

// ---------------------------------------------------------------------------
// R10 = exact replication of the measured-best R7 config (104.8 us).
// Deviations both regressed: QT=16 (+14.3, occupancy halved), TAB=2048/
// NBIN=32 (+6.4). Keep: 4096-cell single-fp32 |MLP| table (ds_read_b32
// gather, 2-way bank aliasing = free), counting sort by (chan, pos-bin),
// CDF window skip, strict dd<WINDOW mask for exactness.
// ---------------------------------------------------------------------------
__global__ __launch_bounds__(256) void preprocess(
    const float* __restrict__ key_pos,
    const float* __restrict__ values,
    const int*   __restrict__ key_chan,
    const float* __restrict__ w0, const float* __restrict__ b0,
    const float* __restrict__ w1, const float* __restrict__ b1,
    const float* __restrict__ w2, const float* __restrict__ b2,
    const float* __restrict__ w3, const float* __restrict__ b3,
    float* __restrict__ tab,
    float2* __restrict__ sorted,
    int*    __restrict__ bins)
{
    const int tid = threadIdx.x;

    if (blockIdx.x < 16) {
        // ---- table build: |f| at cell center ----
        const int i = blockIdx.x * 256 + tid;
        const float x = ((float)i + 0.5f) * (1.0f / SCALE_);
        float h[H_], g[H_];
        #pragma unroll
        for (int j = 0; j < H_; ++j)
            h[j] = fmaxf(fmaf(x, w0[j], b0[j]), 0.f);
        #pragma unroll
        for (int j = 0; j < H_; ++j) {
            float a = b1[j];
            #pragma unroll
            for (int k = 0; k < H_; ++k) a = fmaf(w1[j * H_ + k], h[k], a);
            g[j] = fmaxf(a, 0.f);
        }
        #pragma unroll
        for (int j = 0; j < H_; ++j) {
            float a = b2[j];
            #pragma unroll
            for (int k = 0; k < H_; ++k) a = fmaf(w2[j * H_ + k], g[k], a);
            h[j] = fmaxf(a, 0.f);
        }
        float a = b3[0];
        #pragma unroll
        for (int k = 0; k < H_; ++k) a = fmaf(w3[k], h[k], a);
        tab[i] = fabsf(a);
        return;
    }

    // ---- counting sort for one (batch,chan) ----
    const int slot = blockIdx.x - 16;     // 0..15
    const int b    = slot >> 2;
    const int c    = slot & 3;

    __shared__ int   hist[NBIN_ + 1];
    __shared__ int   ofs [NBIN_];
    __shared__ float lpos[SLOT_];
    __shared__ float lval[SLOT_];

    if (tid <= NBIN_) hist[tid] = 0;
    __syncthreads();

    const float* kp = key_pos  + b * NK_;
    const float* vv = values   + b * NK_;
    const int*   cc = key_chan + b * NK_;

    for (int i = tid; i < NK_; i += 256) {
        if (cc[i] == c) {
            const int bin = min((int)(kp[i] * (float)NBIN_), NBIN_ - 1);
            atomicAdd(&hist[bin], 1);
        }
    }
    __syncthreads();

    if (tid == 0) {
        int run = 0;
        #pragma unroll
        for (int t = 0; t < NBIN_; ++t) {
            const int h = hist[t];
            hist[t] = run; ofs[t] = run; run += h;
        }
        hist[NBIN_] = run;
    }
    __syncthreads();

    const int cnt = hist[NBIN_];          // ~512 << SLOT_
    if (tid <= NBIN_) bins[slot * (NBIN_ + 1) + tid] = hist[tid];

    for (int i = tid; i < NK_; i += 256) {
        if (cc[i] == c) {
            const float p   = kp[i];
            const int   bin = min((int)(p * (float)NBIN_), NBIN_ - 1);
            const int   idx = atomicAdd(&ofs[bin], 1);
            lpos[idx] = p; lval[idx] = vv[i];
        }
    }
    __syncthreads();

    for (int i = tid; i < SLOT_; i += 256)
        sorted[slot * SLOT_ + i] =
            (i < cnt) ? make_float2(lpos[i], lval[i]) : make_float2(SENT_, 0.f);
}

// ---------------------------------------------------------------------------
// Main: block = 8 queries of one batch; wave = one query (x2); 1024 blocks
// = 4 blocks/CU (16 waves/CU latency hiding). 16 KB value table in LDS;
// per pair ~9 VALU + 1 dwordx2 + 1 ds_read_b32 gather. CDF indexing skips
// out-of-window bins; strict dd<WINDOW mask exactly kills bin-boundary
// overshoot, overshot slots and sentinels — no lane masks needed.
// ---------------------------------------------------------------------------
__global__ __launch_bounds__(256) void setconv_main(
    const float*  __restrict__ queries,
    const float2* __restrict__ sorted,
    const int*    __restrict__ bins,
    const float*  __restrict__ tab,
    const float*  __restrict__ wd, const float* __restrict__ bd,
    const float*  __restrict__ wr, const float* __restrict__ br,
    float* __restrict__ out)
{
    __shared__ __align__(16) float ltab[TAB_];

    const int tid = threadIdx.x;

    // stage table: 1024 float4s, 4 per thread
    {
        const float4* t4 = (const float4*)tab;
        float4*       l4 = (float4*)ltab;
        #pragma unroll
        for (int i = 0; i < TAB_ / 4 / 256; ++i)
            l4[i * 256 + tid] = t4[i * 256 + tid];
    }
    __syncthreads();

    const int blk  = blockIdx.x;        // 1024 blocks: b = blk>>8, tile = blk&255
    const int b    = blk >> 8;
    const int tile = blk & 255;
    const int wave = tid >> 6;
    const int lane = tid & 63;

    const float wd0 = wd[0];
    const float bd0 = bd[0];

    float wrow[8];
    #pragma unroll
    for (int j = 0; j < 8; ++j) wrow[j] = wr[lane * 8 + j];
    const float brv = br[lane];

    #pragma unroll
    for (int qq = 0; qq < 2; ++qq) {
        const int   qi   = tile * QT_ + wave * 2 + qq;
        const float qpos = queries[b * NQ_ + qi];

        int lo_bin = (int)floorf((qpos - WINDOW_) * (float)NBIN_);
        lo_bin = (lo_bin < 0) ? 0 : ((lo_bin > NBIN_) ? NBIN_ : lo_bin);
        int hi_bin = (int)ceilf((qpos + WINDOW_) * (float)NBIN_);
        hi_bin = (hi_bin < 0) ? 0 : ((hi_bin > NBIN_) ? NBIN_ : hi_bin);

        float dens[4], num[4];
        #pragma unroll
        for (int c = 0; c < 4; ++c) {
            const int slot = b * 4 + c;
            const int* bs  = bins + slot * (NBIN_ + 1);
            const int lo = bs[lo_bin] & ~63;
            const int hi = bs[hi_bin];
            const float2* seg = sorted + slot * SLOT_;

            float d = 0.f, n = 0.f;
            for (int k = lo; k < hi; k += 64) {
                const float2 pv = seg[k + lane];      // may overshoot hi: masked
                const float dd  = fabsf(pv.x - qpos);
                const float t   = fminf(dd * SCALE_, (float)(TAB_ - 1));
                const float tv  = ltab[(int)t];       // ds_read_b32 gather
                const float w   = (dd < WINDOW_) ? tv : 0.f;
                d += w;
                n  = fmaf(w, pv.y, n);
            }
            dens[c] = d; num[c] = n;
        }

        // 64-lane butterfly: every lane ends with the full sums
        #pragma unroll
        for (int off = 32; off >= 1; off >>= 1) {
            #pragma unroll
            for (int c = 0; c < 4; ++c) {
                dens[c] += __shfl_xor(dens[c], off, 64);
                num [c] += __shfl_xor(num [c], off, 64);
            }
        }

        // fused epilogue, redundantly per lane; lane == output channel
        float acc = brv;
        #pragma unroll
        for (int c = 0; c < 4; ++c) {
            const float tgt = num[c] / (dens[c] + 1e-5f);
            const float x   = (dens[c] * 0.1f - 1.0f) * wd0 + bd0;
            const float df  = 1.0f / (1.0f + expf(-x));
            acc = fmaf(wrow[2 * c],     tgt, acc);
            acc = fmaf(wrow[2 * c + 1], df,  acc);
        }
        out[(b * NQ_ + qi) * OUT_ + lane] = acc;
    }
}

extern "C" void kernel_launch(void* const* d_in, const int* in_sizes, int n_in,
                              void* d_out, int out_size, void* d_ws, size_t ws_size,
                              hipStream_t stream) {
    (void)in_sizes; (void)n_in; (void)out_size; (void)ws_size;

    char* ws = (char*)d_ws;
    float*  tab    = (float*) (ws + OFF_TAB);
    float2* sorted = (float2*)(ws + OFF_SORT);
    int*    bins   = (int*)   (ws + OFF_BINS);

    preprocess<<<dim3(32), dim3(256), 0, stream>>>(
        (const float*)d_in[0],  // key_pos
        (const float*)d_in[2],  // values
        (const int*)  d_in[3],  // key_chan
        (const float*)d_in[4],  (const float*)d_in[5],   // w0 b0
        (const float*)d_in[6],  (const float*)d_in[7],   // w1 b1
        (const float*)d_in[8],  (const float*)d_in[9],   // w2 b2
        (const float*)d_in[10], (const float*)d_in[11],  // w3 b3
        tab, sorted, bins);

    setconv_main<<<dim3(B_ * (NQ_ / QT_)), dim3(256), 0, stream>>>(
        (const float*)d_in[1],  // queries
        sorted, bins, tab,
        (const float*)d_in[12], (const float*)d_in[13],  // wd bd
        (const float*)d_in[14], (const float*)d_in[15],  // wr br
        (float*)d_out);
}